// Round 4
// baseline (352.735 us; speedup 1.0000x reference)
//
#include <hip/hip_runtime.h>
#include <cstdint>
#include <cstddef>

#define N_ 32
#define H_ 56
#define W_ 56
#define C_ 256
#define HP 58
#define WP 58

typedef int v4i  __attribute__((ext_vector_type(4)));
typedef int v16i __attribute__((ext_vector_type(16)));

// ---------------- kernel 1: weight sign bytes + |k| partial sums ------------
// grid = 36 (idx = tap*4 + quarter), block = 256 (co).
// wi8 layout: [tap][kc(8)][co(256)][32 ci bytes], ci = kc*32 + e (natural order)
// -> bconv B-fragment (col = lane&31 = co, bytes (lane>>5)*16..+15) is one
//    dwordx4, and the whole wave's fragment load is a contiguous 1 KB.
__global__ __launch_bounds__(256) void pack_w(const float* __restrict__ k,
                                              signed char* __restrict__ wi8,
                                              float* __restrict__ palpha) {
    int idx = blockIdx.x;
    int p = idx >> 2, q = idx & 3;       // tap, ci-quarter
    int co = threadIdx.x;
    float s = 0.f;
    #pragma unroll
    for (int half = 0; half < 2; ++half) {
        int kc = q * 2 + half;
        unsigned wrd[8];
        #pragma unroll
        for (int e = 0; e < 8; ++e) {
            unsigned wv = 0;
            #pragma unroll
            for (int j = 0; j < 4; ++j) {
                float v = k[(size_t)(p * 256 + kc * 32 + e * 4 + j) * 256 + co];
                s += fabsf(v);
                wv |= ((v > 0.f) ? 0x01u : 0xFFu) << (8 * j);
            }
            wrd[e] = wv;
        }
        v4i lo = {(int)wrd[0], (int)wrd[1], (int)wrd[2], (int)wrd[3]};
        v4i hi = {(int)wrd[4], (int)wrd[5], (int)wrd[6], (int)wrd[7]};
        size_t base = ((size_t)(p * 8 + kc) * 256 + co) * 2;
        ((v4i*)wi8)[base]     = lo;
        ((v4i*)wi8)[base + 1] = hi;
    }
    palpha[idx * 256 + co] = s;
}

// ---------------- kernel 2: fused pack + implicit-GEMM i8-MFMA conv ---------
// Block = 256 thr (4 waves), tile M=112 (2 output rows, pad 128) x N=256,
// K = 2304. Waves as 2(M) x 2(N); each wave 2 M-tiles x 4 N-tiles -> 8 MFMAs
// per (tap,kc) step from 2 ds_read + 4 global loads. Rationale (round-2 PMC):
// VGPR=52 proved the compiler discards source-level prefetch; MfmaUtil 21% ==
// pure load-latency stall. 8 MFMAs/step = ~293 cyc matrix-pipe issue vs ~300
// cyc load latency -> one wave self-hides ~50%, 2 waves/SIMD saturate without
// any software pipelining. acc = 128 AGPR -> ~200 unified regs, 2 blocks/CU
// (one block's pack-prologue overlaps the other's K-loop).
__device__ __forceinline__ void epilogue(const v16i& acc, int mb, int svar,
                                         const float* bS, float alpha, float bv,
                                         int co, size_t obase,
                                         float* __restrict__ out) {
    #pragma unroll
    for (int r = 0; r < 16; ++r) {
        int row = (r & 3) + 8 * (r >> 2) + 4 * svar;   // verified 32x32 C/D map
        int m = mb + row;
        if (m < 112) {
            int hl = (m >= 56);
            int w = m - 56 * hl;
            float val = (float)acc[r] * (bS[m] * alpha) + bv;
            out[obase + ((size_t)hl * W_ + w) * C_ + co] = val;
        }
    }
}

__global__ __launch_bounds__(256, 2) void bconv(
        const float4* __restrict__ x4,
        const signed char* __restrict__ wi8, const float* __restrict__ palpha,
        const float* __restrict__ bias, float* __restrict__ out) {
    int bid = blockIdx.x;
    int bi = (bid & 7) * 112 + (bid >> 3);   // XCD swizzle (896 = 8*112, bijective)
    int n = bi / 28;
    int hb = (bi - n * 28) * 2;              // output rows hb, hb+1

    int tid = threadIdx.x;
    int lane = tid & 63, wid = tid >> 6;     // 4 waves
    int wm = wid >> 1, wn = wid & 1;
    int l31 = lane & 31, svar = lane >> 5;

    __shared__ __align__(16) signed char xs[4 * WP * 256];   // 59,392 B swizzled
    __shared__ float brow[4 * WP];
    __shared__ float bS[112];

    // ---- fused pack_x: binarize 4 padded rows into swizzled LDS + beta ----
    // 232 pixels, 58 per wave. Lane covers channels 4*lane..4*lane+3; the
    // 4 sign bytes land at slot (lane>>2)^(pp&15), byte (lane&3)*4.
    {
        int sl4 = lane >> 2;
        int bo  = (lane & 3) << 2;
        for (int i = 0; i < 58; ++i) {
            int pp = wid + 4 * i;            // 0..231
            int r = pp / WP, xc = pp - r * WP;
            int ypad = hb + r;
            bool inb = (ypad >= 1 && ypad <= H_ && xc >= 1 && xc <= W_);
            float4 v = make_float4(0.f, 0.f, 0.f, 0.f);
            if (inb)
                v = x4[(((size_t)n * H_ + (ypad - 1)) * W_ + (xc - 1)) * 64 + lane];
            unsigned wb = ((v.x > 0.f) ? 0x01u : 0xFFu)
                        | (((v.y > 0.f) ? 0x01u : 0xFFu) << 8)
                        | (((v.z > 0.f) ? 0x01u : 0xFFu) << 16)
                        | (((v.w > 0.f) ? 0x01u : 0xFFu) << 24);
            *(unsigned*)&xs[pp * 256 + ((sl4 ^ (pp & 15)) << 4) + bo] = wb;
            float s = fabsf(v.x) + fabsf(v.y) + fabsf(v.z) + fabsf(v.w);
            #pragma unroll
            for (int m = 32; m >= 1; m >>= 1) s += __shfl_xor(s, m, 64);
            if (lane == 0) brow[pp] = s * (1.f / 256.f);
        }
    }
    __syncthreads();

    // 3x3 window sums of beta (the avg_pool) for the 112 output pixels
    if (tid < 112) {
        int r = (tid >= 56);
        int w = tid - 56 * r;
        float s = 0.f;
        #pragma unroll
        for (int rr = 0; rr < 3; ++rr)
            #pragma unroll
            for (int d = 0; d < 3; ++d) s += brow[(r + rr) * WP + w + d];
        bS[tid] = s * (1.f / 9.f);
    }

    // per-lane pixel bases for this wave's two M-tiles (A row = lane&31)
    int m0 = wm * 64 + l31;                       // <= 95, always valid
    int m1 = m0 + 32;
    int m1e = m1 < 112 ? m1 : 111;                // pad lanes clamp, masked at store
    int hl0 = (m0 >= 56), hl1 = (m1e >= 56);
    int pb0 = hl0 * WP + (m0 - 56 * hl0);
    int pb1 = hl1 * WP + (m1e - 56 * hl1);

    // B fragment base: cols wn*128 + t*32 + l31, t in [0,4)
    int vbb = (wn * 128 + l31) * 2 + svar;

    v16i acc0[4], acc1[4];
    #pragma unroll
    for (int t = 0; t < 4; ++t) {
        acc0[t] = (v16i){0,0,0,0,0,0,0,0,0,0,0,0,0,0,0,0};
        acc1[t] = acc0[t];
    }

    const v4i* xsv = (const v4i*)xs;
    const v4i* wv  = (const v4i*)wi8;

    for (int tap = 0; tap < 9; ++tap) {
        int kh = (tap * 11) >> 5;                 // tap/3 for tap in [0,9)
        int kw = tap - kh * 3;
        int p0 = pb0 + kh * WP + kw;
        int p1 = pb1 + kh * WP + kw;
        int a0 = p0 << 4, x0 = p0 & 15;
        int a1 = p1 << 4, x1 = p1 & 15;
        const v4i* bq = wv + (size_t)tap * 4096;
        #pragma unroll
        for (int kc = 0; kc < 8; ++kc) {
            v4i B0 = bq[kc * 512 + vbb];
            v4i B1 = bq[kc * 512 + vbb + 64];
            v4i B2 = bq[kc * 512 + vbb + 128];
            v4i B3 = bq[kc * 512 + vbb + 192];
            int sl = kc * 2 + svar;
            v4i A0 = xsv[a0 | (sl ^ x0)];
            v4i A1 = xsv[a1 | (sl ^ x1)];
            acc0[0] = __builtin_amdgcn_mfma_i32_32x32x32_i8(A0, B0, acc0[0], 0, 0, 0);
            acc1[0] = __builtin_amdgcn_mfma_i32_32x32x32_i8(A1, B0, acc1[0], 0, 0, 0);
            acc0[1] = __builtin_amdgcn_mfma_i32_32x32x32_i8(A0, B1, acc0[1], 0, 0, 0);
            acc1[1] = __builtin_amdgcn_mfma_i32_32x32x32_i8(A1, B1, acc1[1], 0, 0, 0);
            acc0[2] = __builtin_amdgcn_mfma_i32_32x32x32_i8(A0, B2, acc0[2], 0, 0, 0);
            acc1[2] = __builtin_amdgcn_mfma_i32_32x32x32_i8(A1, B2, acc1[2], 0, 0, 0);
            acc0[3] = __builtin_amdgcn_mfma_i32_32x32x32_i8(A0, B3, acc0[3], 0, 0, 0);
            acc1[3] = __builtin_amdgcn_mfma_i32_32x32x32_i8(A1, B3, acc1[3], 0, 0, 0);
        }
    }

    __syncthreads();   // bS visible to all waves

    float as[4], bvv[4];
    #pragma unroll
    for (int t = 0; t < 4; ++t) {
        int co = wn * 128 + t * 32 + l31;
        float s = 0.f;
        for (int i = 0; i < 36; ++i) s += palpha[i * 256 + co];
        as[t] = s * (1.f / 2304.f);
        bvv[t] = bias[co];
    }

    size_t obase = (size_t)(n * H_ + hb) * W_ * C_;
    #pragma unroll
    for (int t = 0; t < 4; ++t) {
        int co = wn * 128 + t * 32 + l31;
        epilogue(acc0[t], wm * 64,      svar, bS, as[t], bvv[t], co, obase, out);
        epilogue(acc1[t], wm * 64 + 32, svar, bS, as[t], bvv[t], co, obase, out);
    }
}

extern "C" void kernel_launch(void* const* d_in, const int* in_sizes, int n_in,
                              void* d_out, int out_size, void* d_ws, size_t ws_size,
                              hipStream_t stream) {
    const float* x    = (const float*)d_in[0];
    const float* k    = (const float*)d_in[1];
    const float* bias = (const float*)d_in[2];
    float* out = (float*)d_out;

    char* ws = (char*)d_ws;
    signed char* wi8    = (signed char*)(ws);               // 589,824 B
    float*       palpha = (float*)(ws + 589824);            //  36,864 B (total ~627 KB)

    pack_w<<<36, 256, 0, stream>>>(k, wi8, palpha);
    bconv<<<896, 256, 0, stream>>>((const float4*)x, wi8, palpha, bias, out);
}

// Round 5
// 258.077 us; speedup vs baseline: 1.3668x; 1.3668x over previous
//
#include <hip/hip_runtime.h>
#include <cstdint>
#include <cstddef>

#define N_ 32
#define H_ 56
#define W_ 56
#define C_ 256
#define HP 58
#define WP 58

typedef int v4i  __attribute__((ext_vector_type(4)));
typedef int v16i __attribute__((ext_vector_type(16)));

// ---------------- kernel 1: weight sign bytes + |k| partial sums ------------
// wi8 layout: [tap][kc(8)][co(256)][32 ci bytes] -> linear in (tap,kc):
// bconv's B stream advances by exactly 8192 B per K-step, enabling a single
// incremented voffset for the asm-pinned prefetch.
__global__ __launch_bounds__(256) void pack_w(const float* __restrict__ k,
                                              signed char* __restrict__ wi8,
                                              float* __restrict__ palpha) {
    int idx = blockIdx.x;
    int p = idx >> 2, q = idx & 3;       // tap, ci-quarter
    int co = threadIdx.x;
    float s = 0.f;
    #pragma unroll
    for (int half = 0; half < 2; ++half) {
        int kc = q * 2 + half;
        unsigned wrd[8];
        #pragma unroll
        for (int e = 0; e < 8; ++e) {
            unsigned wv = 0;
            #pragma unroll
            for (int j = 0; j < 4; ++j) {
                float v = k[(size_t)(p * 256 + kc * 32 + e * 4 + j) * 256 + co];
                s += fabsf(v);
                wv |= ((v > 0.f) ? 0x01u : 0xFFu) << (8 * j);
            }
            wrd[e] = wv;
        }
        v4i lo = {(int)wrd[0], (int)wrd[1], (int)wrd[2], (int)wrd[3]};
        v4i hi = {(int)wrd[4], (int)wrd[5], (int)wrd[6], (int)wrd[7]};
        size_t base = ((size_t)(p * 8 + kc) * 256 + co) * 2;
        ((v4i*)wi8)[base]     = lo;
        ((v4i*)wi8)[base + 1] = hi;
    }
    palpha[idx * 256 + co] = s;
}

// ---------------- kernel 2: fused pack + implicit-GEMM i8-MFMA conv ---------
// Block = 512 thr (8 waves, best measured shape: r1 123.6us), waves 2(M)x4(N),
// each wave 2x2 tiles of 32x32x32 i8 MFMA (64 acc AGPR, 4 waves/SIMD).
// Round-2/4 PMC proved the compiler neither preserves source prefetch (r2:
// VGPR=52, loads sunk) nor batches loads under pressure (r4: 128 regs, loads
// serialized, 2150 cyc/step). Fix: asm-pinned B prefetch -- each wave issues
// next step's 2 B fragments via asm volatile global_load_dwordx4, then
// s_waitcnt vmcnt(2) + sched_barrier(0) (rule 18) before the MFMAs that
// consume the current fragments. B(t+1) flies across step t's 147 cyc of
// MFMA issue; 4 waves/SIMD cover the remainder.
__device__ __forceinline__ void epilogue(const v16i& acc, int mb, int svar,
                                         const float* bS, float alpha, float bv,
                                         int co, size_t obase,
                                         float* __restrict__ out) {
    #pragma unroll
    for (int r = 0; r < 16; ++r) {
        int row = (r & 3) + 8 * (r >> 2) + 4 * svar;   // verified 32x32 C/D map
        int m = mb + row;
        if (m < 112) {
            int hl = (m >= 56);
            int w = m - 56 * hl;
            float val = (float)acc[r] * (bS[m] * alpha) + bv;
            out[obase + ((size_t)hl * W_ + w) * C_ + co] = val;
        }
    }
}

__global__ __launch_bounds__(512, 4) void bconv(
        const float4* __restrict__ x4,
        const signed char* __restrict__ wi8, const float* __restrict__ palpha,
        const float* __restrict__ bias, float* __restrict__ out) {
    int bid = blockIdx.x;
    int bi = (bid & 7) * 112 + (bid >> 3);   // XCD swizzle (896 = 8*112, bijective)
    int n = bi / 28;
    int hb = (bi - n * 28) * 2;              // output rows hb, hb+1

    int tid = threadIdx.x;
    int lane = tid & 63, wid = tid >> 6;     // 8 waves
    int wm = wid >> 2, wn = wid & 3;
    int l31 = lane & 31, svar = lane >> 5;

    __shared__ __align__(16) signed char xs[4 * WP * 256];   // 59,392 B swizzled
    __shared__ float brow[4 * WP];
    __shared__ float bS[112];

    // ---- fused pack_x: binarize 4 padded rows into swizzled LDS + beta ----
    // 232 pixels, 29 per wave. Lane covers channels 4*lane..4*lane+3; the
    // 4 sign bytes land at slot (lane>>2)^(pp&15), byte (lane&3)*4.
    {
        int sl4 = lane >> 2;
        int bo  = (lane & 3) << 2;
        for (int i = 0; i < 29; ++i) {
            int pp = wid + 8 * i;            // 0..231
            int r = pp / WP, xc = pp - r * WP;
            int ypad = hb + r;
            bool inb = (ypad >= 1 && ypad <= H_ && xc >= 1 && xc <= W_);
            float4 v = make_float4(0.f, 0.f, 0.f, 0.f);
            if (inb)
                v = x4[(((size_t)n * H_ + (ypad - 1)) * W_ + (xc - 1)) * 64 + lane];
            unsigned wb = ((v.x > 0.f) ? 0x01u : 0xFFu)
                        | (((v.y > 0.f) ? 0x01u : 0xFFu) << 8)
                        | (((v.z > 0.f) ? 0x01u : 0xFFu) << 16)
                        | (((v.w > 0.f) ? 0x01u : 0xFFu) << 24);
            *(unsigned*)&xs[pp * 256 + ((sl4 ^ (pp & 15)) << 4) + bo] = wb;
            float s = fabsf(v.x) + fabsf(v.y) + fabsf(v.z) + fabsf(v.w);
            #pragma unroll
            for (int m = 32; m >= 1; m >>= 1) s += __shfl_xor(s, m, 64);
            if (lane == 0) brow[pp] = s * (1.f / 256.f);
        }
    }
    __syncthreads();

    // 3x3 window sums of beta (the avg_pool) for the 112 output pixels
    if (tid < 112) {
        int r = (tid >= 56);
        int w = tid - 56 * r;
        float s = 0.f;
        #pragma unroll
        for (int rr = 0; rr < 3; ++rr)
            #pragma unroll
            for (int d = 0; d < 3; ++d) s += brow[(r + rr) * WP + w + d];
        bS[tid] = s * (1.f / 9.f);
    }

    // per-lane pixel bases for this wave's two M-tiles (A row = lane&31)
    int m0 = wm * 64 + l31;                       // <= 95, always valid
    int m1 = m0 + 32;
    int m1e = m1 < 112 ? m1 : 111;                // pad lanes clamp, masked at store
    int hl0 = (m0 >= 56), hl1 = (m1e >= 56);
    int pb0 = hl0 * WP + (m0 - 56 * hl0);
    int pb1 = hl1 * WP + (m1e - 56 * hl1);

    int co0 = wn * 64 + l31, co1 = co0 + 32;      // B col = lane&31
    int vb0 = (co0 * 2 + svar);                   // v4i index; frag 2 at +64

    v16i acc00 = {0,0,0,0,0,0,0,0,0,0,0,0,0,0,0,0};
    v16i acc01 = acc00, acc10 = acc00, acc11 = acc00;

    const v4i* xsv = (const v4i*)xs;
    uint64_t wbase = (uint64_t)(uintptr_t)wi8;
    unsigned voff = (unsigned)vb0 * 16;           // byte offset, +8192 per step

    // preload step 0's B fragments (asm: compiler cannot sink or delete)
    v4i Bc0, Bc1;
    asm volatile("global_load_dwordx4 %0, %2, %3\n\t"
                 "global_load_dwordx4 %1, %2, %3 offset:1024"
                 : "=&v"(Bc0), "=&v"(Bc1) : "v"(voff), "s"(wbase));
    voff += 8192;

    for (int tap = 0; tap < 9; ++tap) {
        int kh = (tap * 11) >> 5;                 // tap/3 for tap in [0,9)
        int kw = tap - kh * 3;
        int p0 = pb0 + kh * WP + kw;
        int p1 = pb1 + kh * WP + kw;
        int a0 = p0 << 4, x0 = p0 & 15;
        int a1 = p1 << 4, x1 = p1 & 15;
        #pragma unroll
        for (int kc = 0; kc < 8; ++kc) {
            // issue B(t+1); last global step issues a dummy (drained post-loop)
            v4i Bn0, Bn1;
            asm volatile("global_load_dwordx4 %0, %2, %3\n\t"
                         "global_load_dwordx4 %1, %2, %3 offset:1024"
                         : "=&v"(Bn0), "=&v"(Bn1) : "v"(voff), "s"(wbase));
            voff += 8192;
            int sl = kc * 2 + svar;
            v4i A0 = xsv[a0 | (sl ^ x0)];
            v4i A1 = xsv[a1 | (sl ^ x1)];
            // wait until only B(t+1)'s 2 loads are outstanding -> B(t) ready
            asm volatile("s_waitcnt vmcnt(2)" ::: "memory");
            __builtin_amdgcn_sched_barrier(0);
            acc00 = __builtin_amdgcn_mfma_i32_32x32x32_i8(A0, Bc0, acc00, 0, 0, 0);
            acc10 = __builtin_amdgcn_mfma_i32_32x32x32_i8(A1, Bc0, acc10, 0, 0, 0);
            acc01 = __builtin_amdgcn_mfma_i32_32x32x32_i8(A0, Bc1, acc01, 0, 0, 0);
            acc11 = __builtin_amdgcn_mfma_i32_32x32x32_i8(A1, Bc1, acc11, 0, 0, 0);
            Bc0 = Bn0; Bc1 = Bn1;
        }
    }

    // drain the final dummy prefetch BEFORE its dest regs can be reused
    asm volatile("s_waitcnt vmcnt(0)" ::: "memory");
    __builtin_amdgcn_sched_barrier(0);

    __syncthreads();   // bS visible to all waves

    float a0s = 0.f, a1s = 0.f;
    for (int i = 0; i < 36; ++i) {
        a0s += palpha[i * 256 + co0];
        a1s += palpha[i * 256 + co1];
    }
    a0s *= (1.f / 2304.f);
    a1s *= (1.f / 2304.f);
    float bv0 = bias[co0], bv1 = bias[co1];

    size_t obase = (size_t)(n * H_ + hb) * W_ * C_;
    epilogue(acc00, wm * 64,      svar, bS, a0s, bv0, co0, obase, out);
    epilogue(acc01, wm * 64,      svar, bS, a1s, bv1, co1, obase, out);
    epilogue(acc10, wm * 64 + 32, svar, bS, a0s, bv0, co0, obase, out);
    epilogue(acc11, wm * 64 + 32, svar, bS, a1s, bv1, co1, obase, out);
}

extern "C" void kernel_launch(void* const* d_in, const int* in_sizes, int n_in,
                              void* d_out, int out_size, void* d_ws, size_t ws_size,
                              hipStream_t stream) {
    const float* x    = (const float*)d_in[0];
    const float* k    = (const float*)d_in[1];
    const float* bias = (const float*)d_in[2];
    float* out = (float*)d_out;

    char* ws = (char*)d_ws;
    signed char* wi8    = (signed char*)(ws);               // 589,824 B
    float*       palpha = (float*)(ws + 589824);            //  36,864 B (total ~627 KB)

    pack_w<<<36, 256, 0, stream>>>(k, wi8, palpha);
    bconv<<<896, 512, 0, stream>>>((const float4*)x, wi8, palpha, bias, out);
}